// Round 3
// baseline (523.292 us; speedup 1.0000x reference)
//
#include <hip/hip_runtime.h>
#include <math.h>

// Problem constants (B=16, N=M=2048, eps=0.05, 10 sinkhorn iters)
#define NPTS    2048
#define NBATCH  16
#define THREADS 256
#define BLOCKS_PER_BATCH 64     // 1024 total blocks, 32 query rows per block
#define ROWS_PER_BLOCK   32

static constexpr float KEPS_L  = 28.853900817779268f;   // log2(e)/eps
static constexpr float LOGMU_L = -11.0f;                 // log_mu*log2(e) = -log2(2048), exact
static constexpr float EPS_LN2 = 0.03465735902799727f;   // eps*ln(2)

// Pack both point clouds as float4 {x,y,z,|p|^2}
__global__ void pack_pts(const float* __restrict__ a, const float* __restrict__ b,
                         float4* __restrict__ pa, float4* __restrict__ pb) {
  int idx = blockIdx.x * blockDim.x + threadIdx.x;
  if (idx < NBATCH * NPTS) {
    float x = a[3*idx], y = a[3*idx+1], z = a[3*idx+2];
    pa[idx] = make_float4(x, y, z, fmaf(x, x, fmaf(y, y, z*z)));
    float u = b[3*idx], v = b[3*idx+1], w = b[3*idx+2];
    pb[idx] = make_float4(u, v, w, fmaf(u, u, fmaf(v, v, w*w)));
  }
}

// One half-iteration of log-domain Sinkhorn:
//   dualQ[j] = -eps * LSE_i[(dualR[i] - C_ij)/eps + log_mu]
// Reduction side R staged in LDS; each wave owns query rows, 4 at a time.
// exp2-domain: v_ij = a2p[i] - KEPS_L*C_ij  (always <= 0 since a2p <= 0),
// LSE = ln2*(A + log2(sum 2^v)).
// CHAMFER: also accumulate sum_j min_i d2_ij into chamPart[blockIdx.x].
template<bool INIT, bool CHAMFER>
__global__ __launch_bounds__(THREADS, 4)
void lse_pass(const float4* __restrict__ pR, const float4* __restrict__ pQ,
              const float* __restrict__ dualR, float* __restrict__ dualQ,
              float* __restrict__ chamPart) {
  __shared__ float4 sx[NPTS];   // 32 KB: reduction-side points
  __shared__ float  sa[NPTS];   //  8 KB: a2p[i] = (f_i/eps + log_mu)*log2e - A
  // total 40960 B exactly -> 4 blocks/CU; sx doubles as reduce scratch.

  const int b    = blockIdx.x >> 6;        // batch
  const int blk  = blockIdx.x & 63;        // block within batch
  const int tid  = threadIdx.x;
  const int lane = tid & 63;
  const int wave = tid >> 6;

  const float4* __restrict__ px = pR + b * NPTS;
  float A;

  if constexpr (INIT) {
    // f == 0: a2[i] = LOGMU_L for all i -> A = LOGMU_L, a2p = 0
    for (int k = tid; k < NPTS; k += THREADS) { sx[k] = px[k]; sa[k] = 0.f; }
    A = LOGMU_L;
    __syncthreads();
  } else {
    const float* __restrict__ fb = dualR + b * NPTS;
    float av[8];
    float lm = -3.4e38f;
#pragma unroll
    for (int u = 0; u < 8; ++u) {
      int k = tid + u * THREADS;
      float a = fmaf(fb[k], KEPS_L, LOGMU_L);
      av[u] = a;
      lm = fmaxf(lm, a);
    }
#pragma unroll
    for (int off = 32; off; off >>= 1) lm = fmaxf(lm, __shfl_xor(lm, off));
    float* scratch = (float*)sx;           // sx not yet staged -> usable
    if (lane == 0) scratch[wave] = lm;
    __syncthreads();
    A = fmaxf(fmaxf(scratch[0], scratch[1]), fmaxf(scratch[2], scratch[3]));
    __syncthreads();                       // done reading scratch before staging
#pragma unroll
    for (int u = 0; u < 8; ++u) {
      int k = tid + u * THREADS;
      sx[k] = px[k];
      sa[k] = av[u] - A;
    }
    __syncthreads();
  }

  const float4* __restrict__ qa = pQ + b * NPTS;
  float* __restrict__ gout = dualQ + b * NPTS;
  const int rowBase = blk * ROWS_PER_BLOCK + wave * 8;  // 8 rows per wave
  float chamAcc = 0.f;

#pragma unroll
  for (int rr = 0; rr < 8; rr += 4) {
    const int j0 = rowBase + rr;
    const float4 q0 = qa[j0 + 0];
    const float4 q1 = qa[j0 + 1];
    const float4 q2 = qa[j0 + 2];
    const float4 q3 = qa[j0 + 3];
    float s0 = 0.f, s1 = 0.f, s2 = 0.f, s3 = 0.f;
    float m0, m1, m2, m3;
    if constexpr (CHAMFER) { m0 = m1 = m2 = m3 = 3.4e38f; }

#pragma unroll 2
    for (int i = lane; i < NPTS; i += 64) {
      const float4 p  = sx[i];
      const float  ap = sa[i];
      {
        float dot = fmaf(p.x, q0.x, fmaf(p.y, q0.y, p.z * q0.z));
        float d2  = fmaxf(fmaf(-2.f, dot, p.w + q0.w), 1e-12f);
        if constexpr (CHAMFER) m0 = fminf(m0, d2);
        s0 += __builtin_amdgcn_exp2f(fmaf(-KEPS_L, __builtin_amdgcn_sqrtf(d2), ap));
      }
      {
        float dot = fmaf(p.x, q1.x, fmaf(p.y, q1.y, p.z * q1.z));
        float d2  = fmaxf(fmaf(-2.f, dot, p.w + q1.w), 1e-12f);
        if constexpr (CHAMFER) m1 = fminf(m1, d2);
        s1 += __builtin_amdgcn_exp2f(fmaf(-KEPS_L, __builtin_amdgcn_sqrtf(d2), ap));
      }
      {
        float dot = fmaf(p.x, q2.x, fmaf(p.y, q2.y, p.z * q2.z));
        float d2  = fmaxf(fmaf(-2.f, dot, p.w + q2.w), 1e-12f);
        if constexpr (CHAMFER) m2 = fminf(m2, d2);
        s2 += __builtin_amdgcn_exp2f(fmaf(-KEPS_L, __builtin_amdgcn_sqrtf(d2), ap));
      }
      {
        float dot = fmaf(p.x, q3.x, fmaf(p.y, q3.y, p.z * q3.z));
        float d2  = fmaxf(fmaf(-2.f, dot, p.w + q3.w), 1e-12f);
        if constexpr (CHAMFER) m3 = fminf(m3, d2);
        s3 += __builtin_amdgcn_exp2f(fmaf(-KEPS_L, __builtin_amdgcn_sqrtf(d2), ap));
      }
    }

    // full-wave xor reductions (all lanes end with the result)
#pragma unroll
    for (int off = 32; off; off >>= 1) {
      s0 += __shfl_xor(s0, off);
      s1 += __shfl_xor(s1, off);
      s2 += __shfl_xor(s2, off);
      s3 += __shfl_xor(s3, off);
      if constexpr (CHAMFER) {
        m0 = fminf(m0, __shfl_xor(m0, off));
        m1 = fminf(m1, __shfl_xor(m1, off));
        m2 = fminf(m2, __shfl_xor(m2, off));
        m3 = fminf(m3, __shfl_xor(m3, off));
      }
    }

    if (lane == 0) {
      gout[j0 + 0] = -EPS_LN2 * (A + __builtin_amdgcn_logf(fmaxf(s0, 1e-37f)));
      gout[j0 + 1] = -EPS_LN2 * (A + __builtin_amdgcn_logf(fmaxf(s1, 1e-37f)));
      gout[j0 + 2] = -EPS_LN2 * (A + __builtin_amdgcn_logf(fmaxf(s2, 1e-37f)));
      gout[j0 + 3] = -EPS_LN2 * (A + __builtin_amdgcn_logf(fmaxf(s3, 1e-37f)));
    }
    if constexpr (CHAMFER) chamAcc += (m0 + m1) + (m2 + m3);
  }

  if constexpr (CHAMFER) {
    __syncthreads();                        // everyone done with sx
    float* scratch = (float*)sx;
    if (lane == 0) scratch[wave] = chamAcc;
    __syncthreads();
    if (tid == 0)
      chamPart[blockIdx.x] = (scratch[0] + scratch[1]) + (scratch[2] + scratch[3]);
  }
}

// Sum f (32768) + g (32768) + chamfer partials (2048) -> scalar.
// f, g, cham are laid out contiguously in ws, so one linear sum of 67584 floats.
__global__ void finalize(const float* __restrict__ base, float* __restrict__ out) {
  __shared__ float red[4];
  float acc = 0.f;
  for (int k = threadIdx.x; k < 67584; k += THREADS) acc += base[k];
#pragma unroll
  for (int off = 32; off; off >>= 1) acc += __shfl_xor(acc, off);
  const int lane = threadIdx.x & 63, wave = threadIdx.x >> 6;
  if (lane == 0) red[wave] = acc;
  __syncthreads();
  if (threadIdx.x == 0) out[0] = (red[0] + red[1]) + (red[2] + red[3]);
}

extern "C" void kernel_launch(void* const* d_in, const int* in_sizes, int n_in,
                              void* d_out, int out_size, void* d_ws, size_t ws_size,
                              hipStream_t stream) {
  const float* outPts = (const float*)d_in[0];
  const float* tgtPts = (const float*)d_in[1];
  float* out = (float*)d_out;

  char* ws = (char*)d_ws;
  float4* pwA = (float4*)ws;                                  // 32768 * 16 B
  float4* pwB = (float4*)(ws + (size_t)NBATCH * NPTS * 16);   // 32768 * 16 B
  float*  f   = (float*)(ws + (size_t)2 * NBATCH * NPTS * 16);// 32768 floats
  float*  g   = f + NBATCH * NPTS;                            // 32768 floats
  float*  cham = g + NBATCH * NPTS;                           // 2048 floats
  // total ws use: ~1.26 MB

  pack_pts<<<dim3(128), dim3(THREADS), 0, stream>>>(outPts, tgtPts, pwA, pwB);

  const dim3 grid(NBATCH * BLOCKS_PER_BATCH);  // 1024
  const dim3 blk(THREADS);

  // iteration 1: f==0 (INIT), fuse both chamfer directions
  lse_pass<true,  true ><<<grid, blk, 0, stream>>>(pwA, pwB, nullptr, g, cham);
  lse_pass<false, true ><<<grid, blk, 0, stream>>>(pwB, pwA, g, f, cham + 1024);
  // iterations 2..10
  for (int t = 1; t < 10; ++t) {
    lse_pass<false, false><<<grid, blk, 0, stream>>>(pwA, pwB, f, g, nullptr);
    lse_pass<false, false><<<grid, blk, 0, stream>>>(pwB, pwA, g, f, nullptr);
  }

  // emd_loss = sum(f) + sum(g) (N==M), plus chamfer partials; contiguous from f.
  finalize<<<dim3(1), blk, 0, stream>>>(f, out);
}

// Round 4
// 448.499 us; speedup vs baseline: 1.1668x; 1.1668x over previous
//
#include <hip/hip_runtime.h>
#include <math.h>

// Problem constants (B=16, N=M=2048, eps=0.05, 10 sinkhorn iters)
#define NPTS    2048
#define NBATCH  16
#define THREADS 256
#define BLOCKS_PER_BATCH 64     // 1024 total blocks, 32 query rows per block
#define ROWS_PER_BLOCK   32
#define ROWS_PER_WAVE    8

static constexpr float KEPS_L  = 28.853900817779268f;   // log2(e)/eps
static constexpr float LOGMU_L = -11.0f;                 // log_mu*log2(e) = -log2(2048), exact
static constexpr float EPS_LN2 = 0.03465735902799727f;   // eps*ln(2)

// Pack both point clouds as float4 {x,y,z,|p|^2}
__global__ void pack_pts(const float* __restrict__ a, const float* __restrict__ b,
                         float4* __restrict__ pa, float4* __restrict__ pb) {
  int idx = blockIdx.x * blockDim.x + threadIdx.x;
  if (idx < NBATCH * NPTS) {
    float x = a[3*idx], y = a[3*idx+1], z = a[3*idx+2];
    pa[idx] = make_float4(x, y, z, fmaf(x, x, fmaf(y, y, z*z)));
    float u = b[3*idx], v = b[3*idx+1], w = b[3*idx+2];
    pb[idx] = make_float4(u, v, w, fmaf(u, u, fmaf(v, v, w*w)));
  }
}

// One half-iteration of log-domain Sinkhorn:
//   dualQ[j] = -eps * LSE_i[(dualR[i] - C_ij)/eps + log_mu]
// exp2-domain with per-batch shift A = max_i a_i, a_i = f_i*K + LOGMU_L:
//   LDS stages {x,y,z,-0.5|p|^2} and weight w_i = 2^(a_i - A)  (<= 1),
//   inner loop per (i,row): t = p.q - 0.5|p|^2 (3 fma), d2 = fma(-2,t,|q|^2),
//   max, sqrt, mul, exp2, fma-acc  -> 7 VALU + 2 trans.
// Each wave owns 8 query rows processed simultaneously (8 indep chains, one
// LDS read pair per i-step). CHAMFER passes also track min_i d2 per row.
template<bool INIT, bool CHAMFER>
__global__ __launch_bounds__(THREADS, 4)
void lse_pass(const float4* __restrict__ pR, const float4* __restrict__ pQ,
              const float* __restrict__ dualR, float* __restrict__ dualQ,
              float* __restrict__ chamPart) {
  __shared__ float4 sx[NPTS];   // 32 KB: {x,y,z,-0.5|p|^2}
  __shared__ float  sw[NPTS];   //  8 KB: 2^(a_i - A)
  // total 40960 B exactly -> 4 blocks/CU; sx doubles as reduce scratch.

  const int b    = blockIdx.x >> 6;        // batch
  const int blk  = blockIdx.x & 63;        // block within batch
  const int tid  = threadIdx.x;
  const int lane = tid & 63;
  const int wave = tid >> 6;

  const float4* __restrict__ px = pR + b * NPTS;
  float A;

  if constexpr (INIT) {
    // f == 0: a_i = LOGMU_L for all i -> A = LOGMU_L, w_i = 1
#pragma unroll
    for (int u = 0; u < 8; ++u) {
      int k = tid + u * THREADS;
      float4 p = px[k];
      sx[k] = make_float4(p.x, p.y, p.z, -0.5f * p.w);
      sw[k] = 1.0f;
    }
    A = LOGMU_L;
    __syncthreads();
  } else {
    const float* __restrict__ fb = dualR + b * NPTS;
    float av[8];
    float lm = -3.4e38f;
#pragma unroll
    for (int u = 0; u < 8; ++u) {
      int k = tid + u * THREADS;
      float a = fmaf(fb[k], KEPS_L, LOGMU_L);
      av[u] = a;
      lm = fmaxf(lm, a);
    }
#pragma unroll
    for (int off = 32; off; off >>= 1) lm = fmaxf(lm, __shfl_xor(lm, off));
    float* scratch = (float*)sx;           // sx not yet staged -> usable
    if (lane == 0) scratch[wave] = lm;
    __syncthreads();
    A = fmaxf(fmaxf(scratch[0], scratch[1]), fmaxf(scratch[2], scratch[3]));
    __syncthreads();                       // done reading scratch before staging
#pragma unroll
    for (int u = 0; u < 8; ++u) {
      int k = tid + u * THREADS;
      float4 p = px[k];
      sx[k] = make_float4(p.x, p.y, p.z, -0.5f * p.w);
      sw[k] = __builtin_amdgcn_exp2f(av[u] - A);
    }
    __syncthreads();
  }

  const float4* __restrict__ qa = pQ + b * NPTS;
  float* __restrict__ gout = dualQ + b * NPTS;
  const int j0 = blk * ROWS_PER_BLOCK + wave * ROWS_PER_WAVE;

  float4 q[ROWS_PER_WAVE];
  float  s[ROWS_PER_WAVE];
  float  m[ROWS_PER_WAVE];
#pragma unroll
  for (int r = 0; r < ROWS_PER_WAVE; ++r) {
    q[r] = qa[j0 + r];
    s[r] = 0.f;
    if constexpr (CHAMFER) m[r] = 3.4e38f;
  }

#pragma unroll 2
  for (int i = lane; i < NPTS; i += 64) {
    const float4 p  = sx[i];
    const float  wi = sw[i];
#pragma unroll
    for (int r = 0; r < ROWS_PER_WAVE; ++r) {
      float t  = fmaf(p.x, q[r].x, fmaf(p.y, q[r].y, fmaf(p.z, q[r].z, p.w)));
      float d2 = fmaxf(fmaf(-2.f, t, q[r].w), 1e-12f);
      if constexpr (CHAMFER) m[r] = fminf(m[r], d2);
      float e = __builtin_amdgcn_exp2f(-KEPS_L * __builtin_amdgcn_sqrtf(d2));
      s[r] = fmaf(e, wi, s[r]);
    }
  }

  // full-wave xor reductions (all lanes end with the result)
#pragma unroll
  for (int off = 32; off; off >>= 1) {
#pragma unroll
    for (int r = 0; r < ROWS_PER_WAVE; ++r) {
      s[r] += __shfl_xor(s[r], off);
      if constexpr (CHAMFER) m[r] = fminf(m[r], __shfl_xor(m[r], off));
    }
  }

  if (lane == 0) {
#pragma unroll
    for (int r = 0; r < ROWS_PER_WAVE; ++r)
      gout[j0 + r] = -EPS_LN2 * (A + __builtin_amdgcn_logf(fmaxf(s[r], 1e-37f)));
  }

  if constexpr (CHAMFER) {
    float chamAcc = 0.f;
#pragma unroll
    for (int r = 0; r < ROWS_PER_WAVE; ++r) chamAcc += m[r];
    __syncthreads();                        // everyone done with sx
    float* scratch = (float*)sx;
    if (lane == 0) scratch[wave] = chamAcc;
    __syncthreads();
    if (tid == 0)
      chamPart[blockIdx.x] = (scratch[0] + scratch[1]) + (scratch[2] + scratch[3]);
  }
}

// Stage 1: 66 blocks x 256 threads, one float4 per thread (66*256*4 = 67584
// floats = f(32768) + g(32768) + cham(2048), contiguous). Fixed-order,
// deterministic.
__global__ void final1(const float4* __restrict__ base, float* __restrict__ part) {
  __shared__ float red[4];
  const int idx = blockIdx.x * THREADS + threadIdx.x;
  float4 v = base[idx];
  float acc = (v.x + v.y) + (v.z + v.w);
#pragma unroll
  for (int off = 32; off; off >>= 1) acc += __shfl_xor(acc, off);
  const int lane = threadIdx.x & 63, wave = threadIdx.x >> 6;
  if (lane == 0) red[wave] = acc;
  __syncthreads();
  if (threadIdx.x == 0) part[blockIdx.x] = (red[0] + red[1]) + (red[2] + red[3]);
}

// Stage 2: one wave sums the 66 partials.
__global__ void final2(const float* __restrict__ part, float* __restrict__ out) {
  const int lane = threadIdx.x;
  float acc = part[lane];                       // 66 entries, lanes 0..63
  if (lane < 2) acc += part[lane + 64];
#pragma unroll
  for (int off = 32; off; off >>= 1) acc += __shfl_xor(acc, off);
  if (lane == 0) out[0] = acc;
}

extern "C" void kernel_launch(void* const* d_in, const int* in_sizes, int n_in,
                              void* d_out, int out_size, void* d_ws, size_t ws_size,
                              hipStream_t stream) {
  const float* outPts = (const float*)d_in[0];
  const float* tgtPts = (const float*)d_in[1];
  float* out = (float*)d_out;

  char* ws = (char*)d_ws;
  float4* pwA = (float4*)ws;                                  // 32768 * 16 B
  float4* pwB = (float4*)(ws + (size_t)NBATCH * NPTS * 16);   // 32768 * 16 B
  float*  f   = (float*)(ws + (size_t)2 * NBATCH * NPTS * 16);// 32768 floats
  float*  g   = f + NBATCH * NPTS;                            // 32768 floats
  float*  cham = g + NBATCH * NPTS;                           // 2048 floats
  float*  part = cham + 2048;                                 // 66 floats
  // total ws use: ~1.26 MB

  pack_pts<<<dim3(128), dim3(THREADS), 0, stream>>>(outPts, tgtPts, pwA, pwB);

  const dim3 grid(NBATCH * BLOCKS_PER_BATCH);  // 1024
  const dim3 blk(THREADS);

  // iteration 1: f==0 (INIT), fuse both chamfer directions
  lse_pass<true,  true ><<<grid, blk, 0, stream>>>(pwA, pwB, nullptr, g, cham);
  lse_pass<false, true ><<<grid, blk, 0, stream>>>(pwB, pwA, g, f, cham + 1024);
  // iterations 2..10
  for (int t = 1; t < 10; ++t) {
    lse_pass<false, false><<<grid, blk, 0, stream>>>(pwA, pwB, f, g, nullptr);
    lse_pass<false, false><<<grid, blk, 0, stream>>>(pwB, pwA, g, f, nullptr);
  }

  // emd_loss = sum(f) + sum(g) (N==M), plus chamfer partials; contiguous from f.
  final1<<<dim3(66), blk, 0, stream>>>((const float4*)f, part);
  final2<<<dim3(1), dim3(64), 0, stream>>>(part, out);
}